// Round 3
// baseline (1290.633 us; speedup 1.0000x reference)
//
#include <hip/hip_runtime.h>

#define F_IN 128
#define H1 32
#define H2 16
#define NPB 128                  // dst-nodes per bucket
#define NBKT 782                 // ceil(100000/128)
#define EPT 16                   // edges per thread in bucketize
#define BZB 256                  // bucketize block size
#define EPB (EPT * BZB)          // 4096 edges per bucketize block

__global__ void k_zero(int* p, int n) {
    int i = blockIdx.x * blockDim.x + threadIdx.x;
    if (i < n) p[i] = 0;
}

__global__ void k_hist(const int* __restrict__ dst, int E, int* __restrict__ cnt) {
    int e = blockIdx.x * blockDim.x + threadIdx.x;
    if (e < E) atomicAdd(&cnt[dst[e]], 1);
}

// block = 128 threads = one bucket: dinv for its nodes + bucket edge total
__global__ void k_dinv_reduce(const int* __restrict__ cnt, int n,
                              float* __restrict__ dinv, int* __restrict__ bucketTotal) {
    int b = blockIdx.x, t = threadIdx.x;
    int i = b * NPB + t;
    int c = (i < n) ? cnt[i] : 0;
    if (i < n) dinv[i] = rsqrtf((float)c + 1.0f);
    int s = c;
    #pragma unroll
    for (int off = 32; off > 0; off >>= 1) s += __shfl_down(s, off);
    __shared__ int ws2[2];
    if ((t & 63) == 0) ws2[t >> 6] = s;
    __syncthreads();
    if (t == 0) bucketTotal[b] = ws2[0] + ws2[1];
}

// single block, 1024 threads: exclusive scan of bucketTotal -> bucketPtr, bucketCursor
__global__ void k_scan(const int* __restrict__ bucketTotal, int nbkt, int E,
                       int* __restrict__ bucketPtr, int* __restrict__ bucketCursor) {
    __shared__ int sh[1024];
    int t = threadIdx.x;
    int own = (t < nbkt) ? bucketTotal[t] : 0;
    sh[t] = own;
    __syncthreads();
    #pragma unroll
    for (int off = 1; off < 1024; off <<= 1) {
        int x = (t >= off) ? sh[t - off] : 0;
        __syncthreads();
        sh[t] += x;
        __syncthreads();
    }
    if (t < nbkt) {
        int excl = sh[t] - own;
        bucketPtr[t] = excl;
        bucketCursor[t] = excl;
        if (t == 0) bucketPtr[nbkt] = E;
    }
}

// block-local counting sort into bucket-grouped packed records (dstLocal:7 | src:17)
__global__ void k_bucketize(const int* __restrict__ src, const int* __restrict__ dst, int E,
                            int* __restrict__ bucketCursor, unsigned* __restrict__ packed) {
    __shared__ int lcnt[NBKT];
    __shared__ int lbase[NBKT];
    int t = threadIdx.x;
    for (int b = t; b < NBKT; b += BZB) lcnt[b] = 0;
    __syncthreads();
    int base = blockIdx.x * EPB;
    unsigned val[EPT]; short bk[EPT]; short rk[EPT];
    #pragma unroll
    for (int i = 0; i < EPT; ++i) {
        int e = base + t + i * BZB;
        if (e < E) {
            int s = src[e], d = dst[e];
            int b = d >> 7;
            bk[i] = (short)b;
            val[i] = ((unsigned)(d & 127) << 17) | (unsigned)s;
            rk[i] = (short)atomicAdd(&lcnt[b], 1);
        } else bk[i] = -1;
    }
    __syncthreads();
    for (int b = t; b < NBKT; b += BZB) {
        int c = lcnt[b];
        if (c > 0) lbase[b] = atomicAdd(&bucketCursor[b], c);
    }
    __syncthreads();
    #pragma unroll
    for (int i = 0; i < EPT; ++i)
        if (bk[i] >= 0) packed[lbase[bk[i]] + (int)rk[i]] = val[i];
}

// g1[v,j] = dinv[v] * sum_k x[v,k] * W1[k,j]
__global__ void k_gemm1(const float* __restrict__ x, const float* __restrict__ W1,
                        const float* __restrict__ dinv, float* __restrict__ g1, int n) {
    __shared__ float Wl[F_IN * H1];  // 16 KB
    for (int t = threadIdx.x; t < F_IN * H1; t += blockDim.x) Wl[t] = W1[t];
    __syncthreads();
    int idx = blockIdx.x * blockDim.x + threadIdx.x;
    int node = idx >> 5, j = idx & 31;
    if (node < n) {
        const float* xr = x + (size_t)node * F_IN;
        float s = 0.f;
        #pragma unroll 8
        for (int k = 0; k < F_IN; ++k) s += xr[k] * Wl[k * H1 + j];
        g1[idx] = dinv[node] * s;
    }
}

// one block per bucket: LDS tile accumulate, fused bias+relu epilogue
__global__ __launch_bounds__(512) void k_agg1(const int* __restrict__ bucketPtr,
        const unsigned* __restrict__ packed, const float* __restrict__ g1,
        const float* __restrict__ dinv, const float* __restrict__ b1,
        float* __restrict__ h1, int n) {
    __shared__ float tile[NPB * H1];  // 16 KB
    int t = threadIdx.x;
    for (int i = t; i < NPB * H1; i += 512) tile[i] = 0.f;
    __syncthreads();
    int bkt = blockIdx.x;
    int beg = bucketPtr[bkt], end = bucketPtr[bkt + 1];
    int j = t & 31, es = t >> 5;  // 16 edge slots
    for (int e = beg + es; e < end; e += 16) {
        unsigned p = packed[e];
        int s = p & 0x1FFFF;
        int dl = p >> 17;
        atomicAdd(&tile[dl * H1 + j], g1[(size_t)s * H1 + j]);
    }
    __syncthreads();
    int nodeBase = bkt * NPB;
    for (int i = t; i < NPB * H1; i += 512) {
        int vl = i >> 5, jj = i & 31;
        int v = nodeBase + vl;
        if (v < n) {
            float a = tile[i] + g1[(size_t)v * H1 + jj];  // + self loop
            float val = dinv[v] * a + b1[jj];
            h1[(size_t)v * H1 + jj] = val > 0.f ? val : 0.f;
        }
    }
}

// g2[v,j] = dinv[v] * sum_k h1[v,k] * W2[k,j]
__global__ void k_gemm2(const float* __restrict__ h1, const float* __restrict__ W2,
                        const float* __restrict__ dinv, float* __restrict__ g2, int n) {
    __shared__ float Wl[H1 * H2];  // 2 KB
    for (int t = threadIdx.x; t < H1 * H2; t += blockDim.x) Wl[t] = W2[t];
    __syncthreads();
    int idx = blockIdx.x * blockDim.x + threadIdx.x;
    int node = idx >> 4, j = idx & 15;
    if (node < n) {
        const float* hr = h1 + (size_t)node * H1;
        float s = 0.f;
        #pragma unroll
        for (int k = 0; k < H1; ++k) s += hr[k] * Wl[k * H2 + j];
        g2[idx] = dinv[node] * s;
    }
}

// one block per bucket: tile accumulate + fully fused output head
__global__ __launch_bounds__(512) void k_agg2(const int* __restrict__ bucketPtr,
        const unsigned* __restrict__ packed, const float* __restrict__ g2,
        const float* __restrict__ dinv, const float* __restrict__ b2,
        const float* __restrict__ Wo, const float* __restrict__ bo,
        float* __restrict__ out, int n) {
    __shared__ float tile[NPB * H2];  // 8 KB
    int t = threadIdx.x;
    for (int i = t; i < NPB * H2; i += 512) tile[i] = 0.f;
    __syncthreads();
    int bkt = blockIdx.x;
    int beg = bucketPtr[bkt], end = bucketPtr[bkt + 1];
    int j = t & 15, es = t >> 4;  // 32 edge slots
    for (int e = beg + es; e < end; e += 32) {
        unsigned p = packed[e];
        int s = p & 0x1FFFF;
        int dl = p >> 17;
        atomicAdd(&tile[dl * H2 + j], g2[(size_t)s * H2 + j]);
    }
    __syncthreads();
    int nodeBase = bkt * NPB;
    int ns = t >> 4;              // 32 node slots, 4 nodes each
    float wv = Wo[j];
    #pragma unroll
    for (int q = 0; q < 4; ++q) {
        int vl = q * 32 + ns;
        int v = nodeBase + vl;
        float r = 0.f;
        if (v < n) {
            float a = tile[vl * H2 + j] + g2[(size_t)v * H2 + j];  // + self loop
            float val = dinv[v] * a + b2[j];
            r = (val > 0.f ? val : 0.f) * wv;
        }
        r += __shfl_down(r, 8);
        r += __shfl_down(r, 4);
        r += __shfl_down(r, 2);
        r += __shfl_down(r, 1);
        if (j == 0 && v < n) out[v] = r + bo[0];
    }
}

extern "C" void kernel_launch(void* const* d_in, const int* in_sizes, int n_in,
                              void* d_out, int out_size, void* d_ws, size_t ws_size,
                              hipStream_t stream) {
    const float* x  = (const float*)d_in[0];
    const int*   ei = (const int*)d_in[1];
    const float* W1 = (const float*)d_in[2];
    const float* b1 = (const float*)d_in[3];
    const float* W2 = (const float*)d_in[4];
    const float* b2 = (const float*)d_in[5];
    const float* Wo = (const float*)d_in[6];
    const float* bo = (const float*)d_in[7];
    float* out = (float*)d_out;

    const int n = in_sizes[0] / F_IN;   // 100000
    const int E = in_sizes[1] / 2;      // 3200000
    const int* src = ei;
    const int* dst = ei + E;
    const int nbkt = (n + NPB - 1) / NPB;  // 782

    auto align = [](size_t s) { return (s + 255) & ~(size_t)255; };
    char* ws = (char*)d_ws;
    size_t o = 0;
    int*      cnt         = (int*)(ws + o); o += align((size_t)n * 4);
    float*    dinv        = (float*)(ws + o); o += align((size_t)n * 4);
    int*      bucketTotal = (int*)(ws + o); o += align((size_t)nbkt * 4);
    int*      bucketPtr   = (int*)(ws + o); o += align((size_t)(nbkt + 1) * 4);
    int*      bucketCur   = (int*)(ws + o); o += align((size_t)nbkt * 4);
    unsigned* packed      = (unsigned*)(ws + o); o += align((size_t)E * 4);
    float*    g1          = (float*)(ws + o); o += align((size_t)n * H1 * 4);
    float*    h1          = (float*)(ws + o); o += align((size_t)n * H1 * 4);
    float*    g2          = g1;  // reuse: g1 dead after k_agg1

    const int B = 256;
    k_zero       <<<(n + B - 1) / B, B, 0, stream>>>(cnt, n);
    k_hist       <<<(E + B - 1) / B, B, 0, stream>>>(dst, E, cnt);
    k_dinv_reduce<<<nbkt, NPB, 0, stream>>>(cnt, n, dinv, bucketTotal);
    k_scan       <<<1, 1024, 0, stream>>>(bucketTotal, nbkt, E, bucketPtr, bucketCur);
    k_gemm1      <<<(n * H1 + B - 1) / B, B, 0, stream>>>(x, W1, dinv, g1, n);
    k_bucketize  <<<(E + EPB - 1) / EPB, BZB, 0, stream>>>(src, dst, E, bucketCur, packed);
    k_agg1       <<<nbkt, 512, 0, stream>>>(bucketPtr, packed, g1, dinv, b1, h1, n);
    k_gemm2      <<<(n * H2 + B - 1) / B, B, 0, stream>>>(h1, W2, dinv, g2, n);
    k_agg2       <<<nbkt, 512, 0, stream>>>(bucketPtr, packed, g2, dinv, b2, Wo, bo, out, n);
}

// Round 4
// 1272.677 us; speedup vs baseline: 1.0141x; 1.0141x over previous
//
#include <hip/hip_runtime.h>

#define F_IN 128
#define H1 32
#define H2 16
#define NPB 128                  // dst-nodes per bucket
#define NBKT 782                 // ceil(100000/128)
#define EPT 16                   // edges per thread in bucketize
#define BZB 256                  // bucketize block size
#define EPB (EPT * BZB)          // 4096 edges per bucketize block
#define SENT 0xFFFFFFFFu

__global__ void k_zero(int* p, int n) {
    int i = blockIdx.x * blockDim.x + threadIdx.x;
    if (i < n) p[i] = 0;
}

__global__ void k_hist(const int* __restrict__ dst, int E, int* __restrict__ cnt) {
    int e = blockIdx.x * blockDim.x + threadIdx.x;
    if (e < E) atomicAdd(&cnt[dst[e]], 1);
}

// block = 128 threads = one bucket: dinv for its nodes + bucket edge total
__global__ void k_dinv_reduce(const int* __restrict__ cnt, int n,
                              float* __restrict__ dinv, int* __restrict__ bucketTotal) {
    int b = blockIdx.x, t = threadIdx.x;
    int i = b * NPB + t;
    int c = (i < n) ? cnt[i] : 0;
    if (i < n) dinv[i] = rsqrtf((float)c + 1.0f);
    int s = c;
    #pragma unroll
    for (int off = 32; off > 0; off >>= 1) s += __shfl_down(s, off);
    __shared__ int ws2[2];
    if ((t & 63) == 0) ws2[t >> 6] = s;
    __syncthreads();
    if (t == 0) bucketTotal[b] = ws2[0] + ws2[1];
}

// single block, 1024 threads: exclusive scan of bucketTotal -> bucketPtr, bucketCursor
__global__ void k_scan(const int* __restrict__ bucketTotal, int nbkt, int E,
                       int* __restrict__ bucketPtr, int* __restrict__ bucketCursor) {
    __shared__ int sh[1024];
    int t = threadIdx.x;
    int own = (t < nbkt) ? bucketTotal[t] : 0;
    sh[t] = own;
    __syncthreads();
    #pragma unroll
    for (int off = 1; off < 1024; off <<= 1) {
        int x = (t >= off) ? sh[t - off] : 0;
        __syncthreads();
        sh[t] += x;
        __syncthreads();
    }
    if (t < nbkt) {
        int excl = sh[t] - own;
        bucketPtr[t] = excl;
        bucketCursor[t] = excl;
        if (t == 0) bucketPtr[nbkt] = E;
    }
}

// block-local counting sort into bucket-grouped packed records (dstLocal:7 | src:17)
__global__ void k_bucketize(const int* __restrict__ src, const int* __restrict__ dst, int E,
                            int* __restrict__ bucketCursor, unsigned* __restrict__ packed) {
    __shared__ int lcnt[NBKT];
    __shared__ int lbase[NBKT];
    int t = threadIdx.x;
    for (int b = t; b < NBKT; b += BZB) lcnt[b] = 0;
    __syncthreads();
    int base = blockIdx.x * EPB;
    unsigned val[EPT]; short bk[EPT]; short rk[EPT];
    #pragma unroll
    for (int i = 0; i < EPT; ++i) {
        int e = base + t + i * BZB;
        if (e < E) {
            int s = src[e], d = dst[e];
            int b = d >> 7;
            bk[i] = (short)b;
            val[i] = ((unsigned)(d & 127) << 17) | (unsigned)s;
            rk[i] = (short)atomicAdd(&lcnt[b], 1);
        } else bk[i] = -1;
    }
    __syncthreads();
    for (int b = t; b < NBKT; b += BZB) {
        int c = lcnt[b];
        if (c > 0) lbase[b] = atomicAdd(&bucketCursor[b], c);
    }
    __syncthreads();
    #pragma unroll
    for (int i = 0; i < EPT; ++i)
        if (bk[i] >= 0) packed[lbase[bk[i]] + (int)rk[i]] = val[i];
}

// g1[v,j] = dinv[v] * sum_k x[v,k] * W1[k,j]
__global__ void k_gemm1(const float* __restrict__ x, const float* __restrict__ W1,
                        const float* __restrict__ dinv, float* __restrict__ g1, int n) {
    __shared__ float Wl[F_IN * H1];  // 16 KB
    for (int t = threadIdx.x; t < F_IN * H1; t += blockDim.x) Wl[t] = W1[t];
    __syncthreads();
    int idx = blockIdx.x * blockDim.x + threadIdx.x;
    int node = idx >> 5, j = idx & 31;
    if (node < n) {
        const float* xr = x + (size_t)node * F_IN;
        float s = 0.f;
        #pragma unroll 8
        for (int k = 0; k < F_IN; ++k) s += xr[k] * Wl[k * H1 + j];
        g1[idx] = dinv[node] * s;
    }
}

// one block per bucket: LDS tile accumulate with 8-deep MLP, fused bias+relu epilogue
__global__ __launch_bounds__(512) void k_agg1(const int* __restrict__ bucketPtr,
        const unsigned* __restrict__ packed, const float* __restrict__ g1,
        const float* __restrict__ dinv, const float* __restrict__ b1,
        float* __restrict__ h1, int n) {
    __shared__ float tile[NPB * H1];  // 16 KB
    int t = threadIdx.x;
    for (int i = t; i < NPB * H1; i += 512) tile[i] = 0.f;
    __syncthreads();
    int bkt = blockIdx.x;
    int beg = bucketPtr[bkt], end = bucketPtr[bkt + 1];
    int j = t & 31, es = t >> 5;  // 16 edge slots
    for (int e0 = beg + es; e0 < end; e0 += 16 * 8) {
        unsigned p[8];
        #pragma unroll
        for (int u = 0; u < 8; ++u) {
            int e = e0 + u * 16;
            p[u] = (e < end) ? packed[e] : SENT;
        }
        float gv[8];
        #pragma unroll
        for (int u = 0; u < 8; ++u)
            if (p[u] != SENT) gv[u] = g1[(size_t)(p[u] & 0x1FFFF) * H1 + j];
        #pragma unroll
        for (int u = 0; u < 8; ++u)
            if (p[u] != SENT) atomicAdd(&tile[(int)(p[u] >> 17) * H1 + j], gv[u]);
    }
    __syncthreads();
    int nodeBase = bkt * NPB;
    for (int i = t; i < NPB * H1; i += 512) {
        int vl = i >> 5, jj = i & 31;
        int v = nodeBase + vl;
        if (v < n) {
            float a = tile[i] + g1[(size_t)v * H1 + jj];  // + self loop
            float val = dinv[v] * a + b1[jj];
            h1[(size_t)v * H1 + jj] = val > 0.f ? val : 0.f;
        }
    }
}

// g2[v,j] = dinv[v] * sum_k h1[v,k] * W2[k,j]
__global__ void k_gemm2(const float* __restrict__ h1, const float* __restrict__ W2,
                        const float* __restrict__ dinv, float* __restrict__ g2, int n) {
    __shared__ float Wl[H1 * H2];  // 2 KB
    for (int t = threadIdx.x; t < H1 * H2; t += blockDim.x) Wl[t] = W2[t];
    __syncthreads();
    int idx = blockIdx.x * blockDim.x + threadIdx.x;
    int node = idx >> 4, j = idx & 15;
    if (node < n) {
        const float* hr = h1 + (size_t)node * H1;
        float s = 0.f;
        #pragma unroll
        for (int k = 0; k < H1; ++k) s += hr[k] * Wl[k * H2 + j];
        g2[idx] = dinv[node] * s;
    }
}

// one block per bucket: tile accumulate with 8-deep MLP + fully fused output head
__global__ __launch_bounds__(512) void k_agg2(const int* __restrict__ bucketPtr,
        const unsigned* __restrict__ packed, const float* __restrict__ g2,
        const float* __restrict__ dinv, const float* __restrict__ b2,
        const float* __restrict__ Wo, const float* __restrict__ bo,
        float* __restrict__ out, int n) {
    __shared__ float tile[NPB * H2];  // 8 KB
    int t = threadIdx.x;
    for (int i = t; i < NPB * H2; i += 512) tile[i] = 0.f;
    __syncthreads();
    int bkt = blockIdx.x;
    int beg = bucketPtr[bkt], end = bucketPtr[bkt + 1];
    int j = t & 15, es = t >> 4;  // 32 edge slots
    for (int e0 = beg + es; e0 < end; e0 += 32 * 8) {
        unsigned p[8];
        #pragma unroll
        for (int u = 0; u < 8; ++u) {
            int e = e0 + u * 32;
            p[u] = (e < end) ? packed[e] : SENT;
        }
        float gv[8];
        #pragma unroll
        for (int u = 0; u < 8; ++u)
            if (p[u] != SENT) gv[u] = g2[(size_t)(p[u] & 0x1FFFF) * H2 + j];
        #pragma unroll
        for (int u = 0; u < 8; ++u)
            if (p[u] != SENT) atomicAdd(&tile[(int)(p[u] >> 17) * H2 + j], gv[u]);
    }
    __syncthreads();
    int nodeBase = bkt * NPB;
    int ns = t >> 4;              // 32 node slots, 4 nodes each
    float wv = Wo[j];
    #pragma unroll
    for (int q = 0; q < 4; ++q) {
        int vl = q * 32 + ns;
        int v = nodeBase + vl;
        float r = 0.f;
        if (v < n) {
            float a = tile[vl * H2 + j] + g2[(size_t)v * H2 + j];  // + self loop
            float val = dinv[v] * a + b2[j];
            r = (val > 0.f ? val : 0.f) * wv;
        }
        r += __shfl_down(r, 8);
        r += __shfl_down(r, 4);
        r += __shfl_down(r, 2);
        r += __shfl_down(r, 1);
        if (j == 0 && v < n) out[v] = r + bo[0];
    }
}

extern "C" void kernel_launch(void* const* d_in, const int* in_sizes, int n_in,
                              void* d_out, int out_size, void* d_ws, size_t ws_size,
                              hipStream_t stream) {
    const float* x  = (const float*)d_in[0];
    const int*   ei = (const int*)d_in[1];
    const float* W1 = (const float*)d_in[2];
    const float* b1 = (const float*)d_in[3];
    const float* W2 = (const float*)d_in[4];
    const float* b2 = (const float*)d_in[5];
    const float* Wo = (const float*)d_in[6];
    const float* bo = (const float*)d_in[7];
    float* out = (float*)d_out;

    const int n = in_sizes[0] / F_IN;   // 100000
    const int E = in_sizes[1] / 2;      // 3200000
    const int* src = ei;
    const int* dst = ei + E;
    const int nbkt = (n + NPB - 1) / NPB;  // 782

    auto align = [](size_t s) { return (s + 255) & ~(size_t)255; };
    char* ws = (char*)d_ws;
    size_t o = 0;
    int*      cnt         = (int*)(ws + o); o += align((size_t)n * 4);
    float*    dinv        = (float*)(ws + o); o += align((size_t)n * 4);
    int*      bucketTotal = (int*)(ws + o); o += align((size_t)nbkt * 4);
    int*      bucketPtr   = (int*)(ws + o); o += align((size_t)(nbkt + 1) * 4);
    int*      bucketCur   = (int*)(ws + o); o += align((size_t)nbkt * 4);
    unsigned* packed      = (unsigned*)(ws + o); o += align((size_t)E * 4);
    float*    g1          = (float*)(ws + o); o += align((size_t)n * H1 * 4);
    float*    h1          = (float*)(ws + o); o += align((size_t)n * H1 * 4);
    float*    g2          = g1;  // reuse: g1 dead after k_agg1

    const int B = 256;
    k_zero       <<<(n + B - 1) / B, B, 0, stream>>>(cnt, n);
    k_hist       <<<(E + B - 1) / B, B, 0, stream>>>(dst, E, cnt);
    k_dinv_reduce<<<nbkt, NPB, 0, stream>>>(cnt, n, dinv, bucketTotal);
    k_scan       <<<1, 1024, 0, stream>>>(bucketTotal, nbkt, E, bucketPtr, bucketCur);
    k_gemm1      <<<(n * H1 + B - 1) / B, B, 0, stream>>>(x, W1, dinv, g1, n);
    k_bucketize  <<<(E + EPB - 1) / EPB, BZB, 0, stream>>>(src, dst, E, bucketCur, packed);
    k_agg1       <<<nbkt, 512, 0, stream>>>(bucketPtr, packed, g1, dinv, b1, h1, n);
    k_gemm2      <<<(n * H2 + B - 1) / B, B, 0, stream>>>(h1, W2, dinv, g2, n);
    k_agg2       <<<nbkt, 512, 0, stream>>>(bucketPtr, packed, g2, dinv, b2, Wo, bo, out, n);
}